// Round 2
// baseline (23378.590 us; speedup 1.0000x reference)
//
#include <hip/hip_runtime.h>

#define T_STEPS 4096
#define HD 512
#define G3HD 1536
#define NCODES 4880
#define NWG 16
#define SENT 0xFFFFFFFFu

// ---------------------------------------------------------------------------
// GEMM1: visit[4096][512] = H^T (4096x4880) @ X_emb (4880x512)
// ---------------------------------------------------------------------------
__global__ __launch_bounds__(256) void gemm1_kernel(const float* __restrict__ H,
                                                    const float* __restrict__ X,
                                                    float* __restrict__ C) {
  __shared__ float As[16][68];
  __shared__ float Bs[16][68];
  const int m0 = blockIdx.x * 64;
  const int n0 = blockIdx.y * 64;
  const int tid = threadIdx.x;
  const int lk = tid >> 4;
  const int lm = (tid & 15) << 2;
  const int tm = (tid & 15) << 2;
  const int tn = (tid >> 4) << 2;
  float acc[4][4] = {};
  for (int k0 = 0; k0 < NCODES; k0 += 16) {
    float4 av = *(const float4*)(H + (size_t)(k0 + lk) * T_STEPS + m0 + lm);
    float4 bv = *(const float4*)(X + (size_t)(k0 + lk) * HD + n0 + lm);
    __syncthreads();
    *(float4*)(&As[lk][lm]) = av;
    *(float4*)(&Bs[lk][lm]) = bv;
    __syncthreads();
#pragma unroll
    for (int kk = 0; kk < 16; ++kk) {
      float4 a = *(const float4*)(&As[kk][tm]);
      float4 b = *(const float4*)(&Bs[kk][tn]);
      float ar[4] = {a.x, a.y, a.z, a.w};
      float br[4] = {b.x, b.y, b.z, b.w};
#pragma unroll
      for (int i = 0; i < 4; ++i)
#pragma unroll
        for (int j = 0; j < 4; ++j) acc[i][j] += ar[i] * br[j];
    }
  }
#pragma unroll
  for (int i = 0; i < 4; ++i) {
    float4 o = make_float4(acc[i][0], acc[i][1], acc[i][2], acc[i][3]);
    *(float4*)(C + (size_t)(m0 + tm + i) * HD + n0 + tn) = o;
  }
}

// ---------------------------------------------------------------------------
// GEMM2: gi[4096][1536] = visit (4096x512) @ W_ih^T (512x1536) + b_ih
// ---------------------------------------------------------------------------
__global__ __launch_bounds__(256) void gemm2_kernel(const float* __restrict__ A,
                                                    const float* __restrict__ B,
                                                    const float* __restrict__ bias,
                                                    float* __restrict__ Cout) {
  __shared__ float As[16][68];
  __shared__ float Bs[16][68];
  const int m0 = blockIdx.x * 64;
  const int n0 = blockIdx.y * 64;
  const int tid = threadIdx.x;
  const int lr = tid >> 2;
  const int lkq = (tid & 3) << 2;
  const int tm = (tid & 15) << 2;
  const int tn = (tid >> 4) << 2;
  float acc[4][4] = {};
  for (int k0 = 0; k0 < HD; k0 += 16) {
    float4 av = *(const float4*)(A + (size_t)(m0 + lr) * HD + k0 + lkq);
    float4 bv = *(const float4*)(B + (size_t)(n0 + lr) * HD + k0 + lkq);
    __syncthreads();
    As[lkq + 0][lr] = av.x; As[lkq + 1][lr] = av.y;
    As[lkq + 2][lr] = av.z; As[lkq + 3][lr] = av.w;
    Bs[lkq + 0][lr] = bv.x; Bs[lkq + 1][lr] = bv.y;
    Bs[lkq + 2][lr] = bv.z; Bs[lkq + 3][lr] = bv.w;
    __syncthreads();
#pragma unroll
    for (int kk = 0; kk < 16; ++kk) {
      float4 a = *(const float4*)(&As[kk][tm]);
      float4 b = *(const float4*)(&Bs[kk][tn]);
      float ar[4] = {a.x, a.y, a.z, a.w};
      float br[4] = {b.x, b.y, b.z, b.w};
#pragma unroll
      for (int i = 0; i < 4; ++i)
#pragma unroll
        for (int j = 0; j < 4; ++j) acc[i][j] += ar[i] * br[j];
    }
  }
  const float b0 = bias[n0 + tn + 0];
  const float b1 = bias[n0 + tn + 1];
  const float b2 = bias[n0 + tn + 2];
  const float b3 = bias[n0 + tn + 3];
#pragma unroll
  for (int i = 0; i < 4; ++i) {
    float4 o = make_float4(acc[i][0] + b0, acc[i][1] + b1, acc[i][2] + b2, acc[i][3] + b3);
    *(float4*)(Cout + (size_t)(m0 + tm + i) * G3HD + n0 + tn) = o;
  }
}

// ---------------------------------------------------------------------------
// Persistent GRU scan with DATA-FLOW sync (no flags, no fences).
// hs is pre-set to 0xFFFFFFFF (-NaN sentinel, unreachable from finite GRU
// math). Each (t,k) slot is written exactly once; consumers poll their own
// 16 h-words with relaxed agent-scope loads until non-sentinel, then compute
// straight from registers. hprev for the gates is stashed to LDS by the two
// threads whose poll slice == this WG's own output slice (their poll at t+1
// can only succeed after this WG's gates stored at t -> race-free).
// ---------------------------------------------------------------------------
__global__ __launch_bounds__(384, 1) void scan_kernel(const float* __restrict__ gi,
                                                      const float* __restrict__ W_hh,
                                                      const float* __restrict__ b_hh,
                                                      const float* __restrict__ w_att,
                                                      float* __restrict__ hs,
                                                      float* __restrict__ logitp) {
  const int g = blockIdx.x;
  const int tid = threadIdx.x;
  const int rg = tid >> 5;   // 0..11 row-group
  const int kc = tid & 31;   // 0..31 k-chunk (16 k each)

  float w[8][16];
#pragma unroll
  for (int r = 0; r < 8; ++r) {
    const int lr = rg * 8 + r;
    const int grow = (lr >> 5) * HD + g * 32 + (lr & 31);
    const float* wp = W_hh + (size_t)grow * HD + kc * 16;
#pragma unroll
    for (int i = 0; i < 16; i += 4) {
      float4 v = *(const float4*)(wp + i);
      w[r][i + 0] = v.x; w[r][i + 1] = v.y; w[r][i + 2] = v.z; w[r][i + 3] = v.w;
    }
  }

  __shared__ float part[96 * 33];
  __shared__ float ghb[96];
  __shared__ float hp_s[32];
  __shared__ float bhh_s[96];

  if (tid < 96) bhh_s[tid] = b_hh[(tid >> 5) * HD + g * 32 + (tid & 31)];
  float wa = 0.f;
  if (tid < 32) wa = w_att[g * 32 + tid];

  unsigned int* hs_u = (unsigned int*)hs;

  for (int t = 0; t < T_STEPS; ++t) {
    // gate-input loads issued early (cached, overlap with poll)
    float gi_r = 0.f, gi_z = 0.f, gi_n = 0.f;
    if (tid < 32) {
      const float* gp = gi + (size_t)t * G3HD + g * 32 + tid;
      gi_r = gp[0];
      gi_z = gp[HD];
      gi_n = gp[2 * HD];
    }

    float h[16];
    if (t == 0) {
#pragma unroll
      for (int i = 0; i < 16; ++i) h[i] = 0.f;
    } else {
      const unsigned int* p = hs_u + (size_t)(t - 1) * HD + kc * 16;
      unsigned int u[16];
      bool ok;
      do {
        ok = true;
#pragma unroll
        for (int i = 0; i < 16; ++i)
          u[i] = __hip_atomic_load(p + i, __ATOMIC_RELAXED, __HIP_MEMORY_SCOPE_AGENT);
#pragma unroll
        for (int i = 0; i < 16; ++i) ok &= (u[i] != SENT);
      } while (!ok);
#pragma unroll
      for (int i = 0; i < 16; ++i) h[i] = __uint_as_float(u[i]);
    }

    // stash this WG's own hprev slice for the gate lanes (words g*32..g*32+31
    // live in k-chunks kc==2g and kc==2g+1)
    if (rg == 0 && (kc >> 1) == g) {
#pragma unroll
      for (int i = 0; i < 16; ++i) hp_s[(kc & 1) * 16 + i] = h[i];
    }

    float acc[8] = {0.f, 0.f, 0.f, 0.f, 0.f, 0.f, 0.f, 0.f};
#pragma unroll
    for (int ii = 0; ii < 16; ++ii) {
      const float hv = h[ii];
#pragma unroll
      for (int r = 0; r < 8; ++r) acc[r] += w[r][ii] * hv;
    }
#pragma unroll
    for (int r = 0; r < 8; ++r) part[(rg * 8 + r) * 33 + kc] = acc[r];
    __syncthreads();

    {
      const int row = tid >> 2;  // 0..95
      const int q = tid & 3;
      float s = 0.f;
#pragma unroll
      for (int i = 0; i < 8; ++i) s += part[row * 33 + q * 8 + i];
      s += __shfl_xor(s, 1);
      s += __shfl_xor(s, 2);
      if (q == 0) ghb[row] = s + bhh_s[row];
    }
    __syncthreads();

    if (tid < 32) {
      const int j = tid;
      const float x_r = gi_r + ghb[j];
      const float x_z = gi_z + ghb[32 + j];
      const float ghn = ghb[64 + j];
      const float r = 1.f / (1.f + expf(-x_r));
      const float z = 1.f / (1.f + expf(-x_z));
      const float n = tanhf(gi_n + r * ghn);
      const float hnew = (1.f - z) * n + z * hp_s[j];
      __hip_atomic_store(hs_u + (size_t)t * HD + g * 32 + j, __float_as_uint(hnew),
                         __ATOMIC_RELAXED, __HIP_MEMORY_SCOPE_AGENT);
      float lp = wa * hnew;
      lp += __shfl_xor(lp, 1);
      lp += __shfl_xor(lp, 2);
      lp += __shfl_xor(lp, 4);
      lp += __shfl_xor(lp, 8);
      lp += __shfl_xor(lp, 16);
      if (j == 0) logitp[t * NWG + g] = lp;
    }
  }
}

// ---------------------------------------------------------------------------
// Softmax over 4096 logits (reduce 16 partials each), write alpha; zero out.
// ---------------------------------------------------------------------------
__global__ __launch_bounds__(256) void softmax_kernel(const float* __restrict__ logitp,
                                                      float* __restrict__ alpha,
                                                      float* __restrict__ out) {
  __shared__ float tmp[4];
  const int tid = threadIdx.x;
  float l[16];
  float m = -1e30f;
#pragma unroll
  for (int i = 0; i < 16; ++i) {
    const int t = i * 256 + tid;
    float s = 0.f;
#pragma unroll
    for (int gg = 0; gg < NWG; ++gg) s += logitp[t * NWG + gg];
    l[i] = s;
    m = fmaxf(m, s);
  }
#pragma unroll
  for (int o = 32; o > 0; o >>= 1) m = fmaxf(m, __shfl_xor(m, o));
  if ((tid & 63) == 0) tmp[tid >> 6] = m;
  __syncthreads();
  m = fmaxf(fmaxf(tmp[0], tmp[1]), fmaxf(tmp[2], tmp[3]));
  __syncthreads();
  float e[16];
  float s = 0.f;
#pragma unroll
  for (int i = 0; i < 16; ++i) {
    e[i] = expf(l[i] - m);
    s += e[i];
  }
#pragma unroll
  for (int o = 32; o > 0; o >>= 1) s += __shfl_xor(s, o);
  if ((tid & 63) == 0) tmp[tid >> 6] = s;
  __syncthreads();
  s = tmp[0] + tmp[1] + tmp[2] + tmp[3];
  const float inv = 1.f / s;
#pragma unroll
  for (int i = 0; i < 16; ++i) alpha[i * 256 + tid] = e[i] * inv;
  out[tid] = 0.f;
  out[256 + tid] = 0.f;
}

// ---------------------------------------------------------------------------
// out[j] = sum_t alpha[t] * hs[t][j].  128 WGs: 2 j-halves x 64 t-chunks.
// ---------------------------------------------------------------------------
__global__ __launch_bounds__(256) void wsum_kernel(const float* __restrict__ alpha,
                                                   const float* __restrict__ hs,
                                                   float* __restrict__ out) {
  const int tid = threadIdx.x;
  const int jblk = (blockIdx.x & 1) * 256;
  const int tc = blockIdx.x >> 1;
  float acc = 0.f;
  for (int tt = 0; tt < 64; ++tt) {
    const int t = tc * 64 + tt;
    acc += alpha[t] * hs[(size_t)t * HD + jblk + tid];
  }
  atomicAdd(&out[jblk + tid], acc);
}

extern "C" void kernel_launch(void* const* d_in, const int* in_sizes, int n_in,
                              void* d_out, int out_size, void* d_ws, size_t ws_size,
                              hipStream_t stream) {
  const float* H     = (const float*)d_in[0];
  // d_in[1] = TE, unused by the reference
  const float* X_emb = (const float*)d_in[2];
  const float* W_ih  = (const float*)d_in[3];
  const float* W_hh  = (const float*)d_in[4];
  const float* b_ih  = (const float*)d_in[5];
  const float* b_hh  = (const float*)d_in[6];
  const float* w_att = (const float*)d_in[7];
  float* out = (float*)d_out;

  char* ws = (char*)d_ws;
  float* visit  = (float*)(ws + 0);          //  8 MB: 4096x512
  float* gi     = (float*)(ws + 8388608);    // 25 MB: 4096x1536
  float* hs     = (float*)(ws + 33554432);   //  8 MB: 4096x512
  float* logitp = (float*)(ws + 41943040);   // 256 KB: 4096x16
  float* alpha  = (float*)(ws + 42205184);   // 16 KB

  // sentinel-fill hs: 0xFFFFFFFF = -NaN, unreachable from finite GRU math
  hipMemsetAsync(hs, 0xFF, (size_t)T_STEPS * HD * sizeof(float), stream);

  gemm1_kernel<<<dim3(64, 8), 256, 0, stream>>>(H, X_emb, visit);
  gemm2_kernel<<<dim3(64, 24), 256, 0, stream>>>(visit, W_ih, b_ih, gi);
  scan_kernel<<<NWG, 384, 0, stream>>>(gi, W_hh, b_hh, w_att, hs, logitp);
  softmax_kernel<<<1, 256, 0, stream>>>(logitp, alpha, out);
  wsum_kernel<<<128, 256, 0, stream>>>(alpha, hs, out);
}

// Round 3
// 7293.845 us; speedup vs baseline: 3.2052x; 3.2052x over previous
//
#include <hip/hip_runtime.h>

#define T_STEPS 4096
#define HD 512
#define G3HD 1536
#define NCODES 4880
#define NWG 16
#define SENT 0xFFFFFFFFu

// ---------------------------------------------------------------------------
// GEMM1: visit[4096][512] = H^T (4096x4880) @ X_emb (4880x512)
// ---------------------------------------------------------------------------
__global__ __launch_bounds__(256) void gemm1_kernel(const float* __restrict__ H,
                                                    const float* __restrict__ X,
                                                    float* __restrict__ C) {
  __shared__ float As[16][68];
  __shared__ float Bs[16][68];
  const int m0 = blockIdx.x * 64;
  const int n0 = blockIdx.y * 64;
  const int tid = threadIdx.x;
  const int lk = tid >> 4;
  const int lm = (tid & 15) << 2;
  const int tm = (tid & 15) << 2;
  const int tn = (tid >> 4) << 2;
  float acc[4][4] = {};
  for (int k0 = 0; k0 < NCODES; k0 += 16) {
    float4 av = *(const float4*)(H + (size_t)(k0 + lk) * T_STEPS + m0 + lm);
    float4 bv = *(const float4*)(X + (size_t)(k0 + lk) * HD + n0 + lm);
    __syncthreads();
    *(float4*)(&As[lk][lm]) = av;
    *(float4*)(&Bs[lk][lm]) = bv;
    __syncthreads();
#pragma unroll
    for (int kk = 0; kk < 16; ++kk) {
      float4 a = *(const float4*)(&As[kk][tm]);
      float4 b = *(const float4*)(&Bs[kk][tn]);
      float ar[4] = {a.x, a.y, a.z, a.w};
      float br[4] = {b.x, b.y, b.z, b.w};
#pragma unroll
      for (int i = 0; i < 4; ++i)
#pragma unroll
        for (int j = 0; j < 4; ++j) acc[i][j] += ar[i] * br[j];
    }
  }
#pragma unroll
  for (int i = 0; i < 4; ++i) {
    float4 o = make_float4(acc[i][0], acc[i][1], acc[i][2], acc[i][3]);
    *(float4*)(C + (size_t)(m0 + tm + i) * HD + n0 + tn) = o;
  }
}

// ---------------------------------------------------------------------------
// GEMM2: gi[4096][1536] = visit (4096x512) @ W_ih^T (512x1536) + b_ih
// ---------------------------------------------------------------------------
__global__ __launch_bounds__(256) void gemm2_kernel(const float* __restrict__ A,
                                                    const float* __restrict__ B,
                                                    const float* __restrict__ bias,
                                                    float* __restrict__ Cout) {
  __shared__ float As[16][68];
  __shared__ float Bs[16][68];
  const int m0 = blockIdx.x * 64;
  const int n0 = blockIdx.y * 64;
  const int tid = threadIdx.x;
  const int lr = tid >> 2;
  const int lkq = (tid & 3) << 2;
  const int tm = (tid & 15) << 2;
  const int tn = (tid >> 4) << 2;
  float acc[4][4] = {};
  for (int k0 = 0; k0 < HD; k0 += 16) {
    float4 av = *(const float4*)(A + (size_t)(m0 + lr) * HD + k0 + lkq);
    float4 bv = *(const float4*)(B + (size_t)(n0 + lr) * HD + k0 + lkq);
    __syncthreads();
    As[lkq + 0][lr] = av.x; As[lkq + 1][lr] = av.y;
    As[lkq + 2][lr] = av.z; As[lkq + 3][lr] = av.w;
    Bs[lkq + 0][lr] = bv.x; Bs[lkq + 1][lr] = bv.y;
    Bs[lkq + 2][lr] = bv.z; Bs[lkq + 3][lr] = bv.w;
    __syncthreads();
#pragma unroll
    for (int kk = 0; kk < 16; ++kk) {
      float4 a = *(const float4*)(&As[kk][tm]);
      float4 b = *(const float4*)(&Bs[kk][tn]);
      float ar[4] = {a.x, a.y, a.z, a.w};
      float br[4] = {b.x, b.y, b.z, b.w};
#pragma unroll
      for (int i = 0; i < 4; ++i)
#pragma unroll
        for (int j = 0; j < 4; ++j) acc[i][j] += ar[i] * br[j];
    }
  }
  const float b0 = bias[n0 + tn + 0];
  const float b1 = bias[n0 + tn + 1];
  const float b2 = bias[n0 + tn + 2];
  const float b3 = bias[n0 + tn + 3];
#pragma unroll
  for (int i = 0; i < 4; ++i) {
    float4 o = make_float4(acc[i][0] + b0, acc[i][1] + b1, acc[i][2] + b2, acc[i][3] + b3);
    *(float4*)(Cout + (size_t)(m0 + tm + i) * G3HD + n0 + tn) = o;
  }
}

// ---------------------------------------------------------------------------
// Persistent GRU scan, XCD-pinned team + light data-flow poll.
// 256 candidate WGs launch; each reads HW_REG_XCC_ID, claims a per-XCD ticket
// (ctrl[0..7]); first XCD to seat NWG WGs CASes itself as winner (ctrl[8]);
// all other WGs exit. The 16-WG team is then entirely on one XCD.
// Per step: wave 0 polls the whole h[t-1] (sentinel 0xFFFFFFFF = -NaN,
// unreachable from finite GRU math; 8 words/lane, relaxed agent loads),
// scatters into LDS transposed; barrier; 12 waves do the 96x512 matvec from
// registers (W_hh slice lives in 128 VGPRs/thread); LDS tree-reduce; gates on
// 32 lanes; publish slice via relaxed agent stores. No flags, no fences.
// ---------------------------------------------------------------------------
__global__ __launch_bounds__(384, 1) void scan_kernel(const float* __restrict__ gi,
                                                      const float* __restrict__ W_hh,
                                                      const float* __restrict__ b_hh,
                                                      const float* __restrict__ w_att,
                                                      float* __restrict__ hs,
                                                      float* __restrict__ logitp,
                                                      int* __restrict__ ctrl) {
  __shared__ int s_role;
  const int tid = threadIdx.x;

  if (tid == 0) {
    int xcd;
    asm volatile("s_getreg_b32 %0, hwreg(HW_REG_XCC_ID)" : "=s"(xcd));
    int role = -1;
    const int slot = atomicAdd(&ctrl[xcd], 1);
    if (slot < NWG) {
      if (slot == NWG - 1) atomicCAS(&ctrl[8], -1, xcd);
      int wnr;
      while ((wnr = __hip_atomic_load(&ctrl[8], __ATOMIC_RELAXED,
                                      __HIP_MEMORY_SCOPE_AGENT)) < 0) {
        __builtin_amdgcn_s_sleep(16);
      }
      if (wnr == xcd) role = slot;
    }
    s_role = role;
  }
  __syncthreads();
  const int g = s_role;
  if (g < 0) return;

  const int rg = tid >> 5;   // 0..11 row-group
  const int kc = tid & 31;   // 0..31 k-chunk (16 k each)

  float w[8][16];
#pragma unroll
  for (int r = 0; r < 8; ++r) {
    const int lr = rg * 8 + r;
    const int grow = (lr >> 5) * HD + g * 32 + (lr & 31);
    const float* wp = W_hh + (size_t)grow * HD + kc * 16;
#pragma unroll
    for (int i = 0; i < 16; i += 4) {
      float4 v = *(const float4*)(wp + i);
      w[r][i + 0] = v.x; w[r][i + 1] = v.y; w[r][i + 2] = v.z; w[r][i + 3] = v.w;
    }
  }

  __shared__ float hT[512];        // transposed: h[k] at hT[(k&15)*32 + (k>>4)]
  __shared__ float part[96 * 33];
  __shared__ float ghb[96];
  __shared__ float bhh_s[96];

  if (tid < 96) bhh_s[tid] = b_hh[(tid >> 5) * HD + g * 32 + (tid & 31)];
  float wa = 0.f;
  if (tid < 32) wa = w_att[g * 32 + tid];

  unsigned int* hs_u = (unsigned int*)hs;

  for (int t = 0; t < T_STEPS; ++t) {
    // gate-input loads issued early (overlap with the poll)
    float gi_r = 0.f, gi_z = 0.f, gi_n = 0.f;
    if (tid < 32) {
      const float* gp = gi + (size_t)t * G3HD + g * 32 + tid;
      gi_r = gp[0];
      gi_z = gp[HD];
      gi_n = gp[2 * HD];
    }

    if (tid < 64) {  // wave 0 polls the full h[t-1]
      float h8[8];
      if (t == 0) {
#pragma unroll
        for (int i = 0; i < 8; ++i) h8[i] = 0.f;
      } else {
        const unsigned int* p = hs_u + (size_t)(t - 1) * HD + tid * 8;
        unsigned int u[8];
        bool ok;
        do {
          ok = true;
#pragma unroll
          for (int i = 0; i < 8; ++i)
            u[i] = __hip_atomic_load(p + i, __ATOMIC_RELAXED, __HIP_MEMORY_SCOPE_AGENT);
#pragma unroll
          for (int i = 0; i < 8; ++i) ok &= (u[i] != SENT);
        } while (!ok);
#pragma unroll
        for (int i = 0; i < 8; ++i) h8[i] = __uint_as_float(u[i]);
      }
#pragma unroll
      for (int i = 0; i < 8; ++i) {
        const int k = tid * 8 + i;
        hT[(k & 15) * 32 + (k >> 4)] = h8[i];
      }
    }
    __syncthreads();  // B1: hT ready

    float acc[8] = {0.f, 0.f, 0.f, 0.f, 0.f, 0.f, 0.f, 0.f};
#pragma unroll
    for (int ii = 0; ii < 16; ++ii) {
      const float hv = hT[ii * 32 + kc];
#pragma unroll
      for (int r = 0; r < 8; ++r) acc[r] += w[r][ii] * hv;
    }
#pragma unroll
    for (int r = 0; r < 8; ++r) part[(rg * 8 + r) * 33 + kc] = acc[r];
    __syncthreads();  // B2: partials ready

    {
      const int row = tid >> 2;  // 0..95
      const int q = tid & 3;
      float s = 0.f;
#pragma unroll
      for (int i = 0; i < 8; ++i) s += part[row * 33 + q * 8 + i];
      s += __shfl_xor(s, 1);
      s += __shfl_xor(s, 2);
      if (q == 0) ghb[row] = s + bhh_s[row];
    }
    __syncthreads();  // B3: ghb ready

    if (tid < 32) {
      const int j = tid;
      const float x_r = gi_r + ghb[j];
      const float x_z = gi_z + ghb[32 + j];
      const float ghn = ghb[64 + j];
      const float r = 1.f / (1.f + expf(-x_r));
      const float z = 1.f / (1.f + expf(-x_z));
      const float n = tanhf(gi_n + r * ghn);
      const float hprev = hT[(j & 15) * 32 + (g * 2 + (j >> 4))];
      const float hnew = (1.f - z) * n + z * hprev;
      __hip_atomic_store(hs_u + (size_t)t * HD + g * 32 + j, __float_as_uint(hnew),
                         __ATOMIC_RELAXED, __HIP_MEMORY_SCOPE_AGENT);
      float lp = wa * hnew;
      lp += __shfl_xor(lp, 1);
      lp += __shfl_xor(lp, 2);
      lp += __shfl_xor(lp, 4);
      lp += __shfl_xor(lp, 8);
      lp += __shfl_xor(lp, 16);
      if (j == 0) logitp[t * NWG + g] = lp;
    }
  }
}

// ---------------------------------------------------------------------------
// Softmax over 4096 logits (reduce 16 partials each), write alpha; zero out.
// ---------------------------------------------------------------------------
__global__ __launch_bounds__(256) void softmax_kernel(const float* __restrict__ logitp,
                                                      float* __restrict__ alpha,
                                                      float* __restrict__ out) {
  __shared__ float tmp[4];
  const int tid = threadIdx.x;
  float l[16];
  float m = -1e30f;
#pragma unroll
  for (int i = 0; i < 16; ++i) {
    const int t = i * 256 + tid;
    float s = 0.f;
#pragma unroll
    for (int gg = 0; gg < NWG; ++gg) s += logitp[t * NWG + gg];
    l[i] = s;
    m = fmaxf(m, s);
  }
#pragma unroll
  for (int o = 32; o > 0; o >>= 1) m = fmaxf(m, __shfl_xor(m, o));
  if ((tid & 63) == 0) tmp[tid >> 6] = m;
  __syncthreads();
  m = fmaxf(fmaxf(tmp[0], tmp[1]), fmaxf(tmp[2], tmp[3]));
  __syncthreads();
  float e[16];
  float s = 0.f;
#pragma unroll
  for (int i = 0; i < 16; ++i) {
    e[i] = expf(l[i] - m);
    s += e[i];
  }
#pragma unroll
  for (int o = 32; o > 0; o >>= 1) s += __shfl_xor(s, o);
  if ((tid & 63) == 0) tmp[tid >> 6] = s;
  __syncthreads();
  s = tmp[0] + tmp[1] + tmp[2] + tmp[3];
  const float inv = 1.f / s;
#pragma unroll
  for (int i = 0; i < 16; ++i) alpha[i * 256 + tid] = e[i] * inv;
  out[tid] = 0.f;
  out[256 + tid] = 0.f;
}

// ---------------------------------------------------------------------------
// out[j] = sum_t alpha[t] * hs[t][j].  128 WGs: 2 j-halves x 64 t-chunks.
// ---------------------------------------------------------------------------
__global__ __launch_bounds__(256) void wsum_kernel(const float* __restrict__ alpha,
                                                   const float* __restrict__ hs,
                                                   float* __restrict__ out) {
  const int tid = threadIdx.x;
  const int jblk = (blockIdx.x & 1) * 256;
  const int tc = blockIdx.x >> 1;
  float acc = 0.f;
  for (int tt = 0; tt < 64; ++tt) {
    const int t = tc * 64 + tt;
    acc += alpha[t] * hs[(size_t)t * HD + jblk + tid];
  }
  atomicAdd(&out[jblk + tid], acc);
}

extern "C" void kernel_launch(void* const* d_in, const int* in_sizes, int n_in,
                              void* d_out, int out_size, void* d_ws, size_t ws_size,
                              hipStream_t stream) {
  const float* H     = (const float*)d_in[0];
  // d_in[1] = TE, unused by the reference
  const float* X_emb = (const float*)d_in[2];
  const float* W_ih  = (const float*)d_in[3];
  const float* W_hh  = (const float*)d_in[4];
  const float* b_ih  = (const float*)d_in[5];
  const float* b_hh  = (const float*)d_in[6];
  const float* w_att = (const float*)d_in[7];
  float* out = (float*)d_out;

  char* ws = (char*)d_ws;
  float* visit  = (float*)(ws + 0);          //  8 MB: 4096x512
  float* gi     = (float*)(ws + 8388608);    // 25 MB: 4096x1536
  float* hs     = (float*)(ws + 33554432);   //  8 MB: 4096x512
  float* logitp = (float*)(ws + 41943040);   // 256 KB: 4096x16
  float* alpha  = (float*)(ws + 42205184);   // 16 KB
  int*   ctrl   = (int*)(ws + 42221568);     // [0..7] per-XCD counters, [8] winner

  // sentinel-fill hs (0xFFFFFFFF = -NaN, unreachable from finite GRU math)
  hipMemsetAsync(hs, 0xFF, (size_t)T_STEPS * HD * sizeof(float), stream);
  hipMemsetAsync(ctrl, 0, 8 * sizeof(int), stream);
  hipMemsetAsync(ctrl + 8, 0xFF, sizeof(int), stream);  // winner = -1

  gemm1_kernel<<<dim3(64, 8), 256, 0, stream>>>(H, X_emb, visit);
  gemm2_kernel<<<dim3(64, 24), 256, 0, stream>>>(visit, W_ih, b_ih, gi);
  scan_kernel<<<256, 384, 0, stream>>>(gi, W_hh, b_hh, w_att, hs, logitp, ctrl);
  softmax_kernel<<<1, 256, 0, stream>>>(logitp, alpha, out);
  wsum_kernel<<<128, 256, 0, stream>>>(alpha, hs, out);
}

// Round 4
// 7131.831 us; speedup vs baseline: 3.2781x; 1.0227x over previous
//
#include <hip/hip_runtime.h>

#define T_STEPS 4096
#define HD 512
#define G3HD 1536
#define NCODES 4880
#define NWG 16
#define SENT 0xFFFFFFFFu

typedef __attribute__((ext_vector_type(2))) float v2f;

// ---------------------------------------------------------------------------
// GEMM1: visit[4096][512] = H^T (4096x4880) @ X_emb (4880x512)
// ---------------------------------------------------------------------------
__global__ __launch_bounds__(256) void gemm1_kernel(const float* __restrict__ H,
                                                    const float* __restrict__ X,
                                                    float* __restrict__ C) {
  __shared__ float As[16][68];
  __shared__ float Bs[16][68];
  const int m0 = blockIdx.x * 64;
  const int n0 = blockIdx.y * 64;
  const int tid = threadIdx.x;
  const int lk = tid >> 4;
  const int lm = (tid & 15) << 2;
  const int tm = (tid & 15) << 2;
  const int tn = (tid >> 4) << 2;
  float acc[4][4] = {};
  for (int k0 = 0; k0 < NCODES; k0 += 16) {
    float4 av = *(const float4*)(H + (size_t)(k0 + lk) * T_STEPS + m0 + lm);
    float4 bv = *(const float4*)(X + (size_t)(k0 + lk) * HD + n0 + lm);
    __syncthreads();
    *(float4*)(&As[lk][lm]) = av;
    *(float4*)(&Bs[lk][lm]) = bv;
    __syncthreads();
#pragma unroll
    for (int kk = 0; kk < 16; ++kk) {
      float4 a = *(const float4*)(&As[kk][tm]);
      float4 b = *(const float4*)(&Bs[kk][tn]);
      float ar[4] = {a.x, a.y, a.z, a.w};
      float br[4] = {b.x, b.y, b.z, b.w};
#pragma unroll
      for (int i = 0; i < 4; ++i)
#pragma unroll
        for (int j = 0; j < 4; ++j) acc[i][j] += ar[i] * br[j];
    }
  }
#pragma unroll
  for (int i = 0; i < 4; ++i) {
    float4 o = make_float4(acc[i][0], acc[i][1], acc[i][2], acc[i][3]);
    *(float4*)(C + (size_t)(m0 + tm + i) * HD + n0 + tn) = o;
  }
}

// ---------------------------------------------------------------------------
// GEMM2: gi[4096][1536] = visit (4096x512) @ W_ih^T (512x1536) + b_ih
// ---------------------------------------------------------------------------
__global__ __launch_bounds__(256) void gemm2_kernel(const float* __restrict__ A,
                                                    const float* __restrict__ B,
                                                    const float* __restrict__ bias,
                                                    float* __restrict__ Cout) {
  __shared__ float As[16][68];
  __shared__ float Bs[16][68];
  const int m0 = blockIdx.x * 64;
  const int n0 = blockIdx.y * 64;
  const int tid = threadIdx.x;
  const int lr = tid >> 2;
  const int lkq = (tid & 3) << 2;
  const int tm = (tid & 15) << 2;
  const int tn = (tid >> 4) << 2;
  float acc[4][4] = {};
  for (int k0 = 0; k0 < HD; k0 += 16) {
    float4 av = *(const float4*)(A + (size_t)(m0 + lr) * HD + k0 + lkq);
    float4 bv = *(const float4*)(B + (size_t)(n0 + lr) * HD + k0 + lkq);
    __syncthreads();
    As[lkq + 0][lr] = av.x; As[lkq + 1][lr] = av.y;
    As[lkq + 2][lr] = av.z; As[lkq + 3][lr] = av.w;
    Bs[lkq + 0][lr] = bv.x; Bs[lkq + 1][lr] = bv.y;
    Bs[lkq + 2][lr] = bv.z; Bs[lkq + 3][lr] = bv.w;
    __syncthreads();
#pragma unroll
    for (int kk = 0; kk < 16; ++kk) {
      float4 a = *(const float4*)(&As[kk][tm]);
      float4 b = *(const float4*)(&Bs[kk][tn]);
      float ar[4] = {a.x, a.y, a.z, a.w};
      float br[4] = {b.x, b.y, b.z, b.w};
#pragma unroll
      for (int i = 0; i < 4; ++i)
#pragma unroll
        for (int j = 0; j < 4; ++j) acc[i][j] += ar[i] * br[j];
    }
  }
  const float b0 = bias[n0 + tn + 0];
  const float b1 = bias[n0 + tn + 1];
  const float b2 = bias[n0 + tn + 2];
  const float b3 = bias[n0 + tn + 3];
#pragma unroll
  for (int i = 0; i < 4; ++i) {
    float4 o = make_float4(acc[i][0] + b0, acc[i][1] + b1, acc[i][2] + b2, acc[i][3] + b3);
    *(float4*)(Cout + (size_t)(m0 + tm + i) * G3HD + n0 + tn) = o;
  }
}

// ---------------------------------------------------------------------------
// Persistent GRU scan, XCD-pinned team (16 WGs on one XCD), data-flow sync.
// 512 thr/WG = 8 waves (exactly 2/SIMD). Thread (rg=tid>>5, kc=tid&31) owns
// 6 rows x 16 k of this WG's 96x512 W_hh slice as float2 pairs (v_pk_fma).
// Per step: wave0 polls h[t-1] (4x u64 relaxed agent loads/lane) against the
// 0xFFFFFFFF sentinel, scatters pairs into hT2 (b64-readable layout); B1;
// 8 waves matvec (48 pk-fma + 8 ds_read_b64 each); shfl_xor tree-reduce (row
// partials live in 32 contiguous lanes -> no LDS, no bank conflicts); B2;
// gates on wave0 lanes<32 with native exp/rcp; relaxed agent store + logit.
// ---------------------------------------------------------------------------
__global__ __launch_bounds__(512, 1) void scan_kernel(const float* __restrict__ gi,
                                                      const float* __restrict__ W_hh,
                                                      const float* __restrict__ b_hh,
                                                      const float* __restrict__ w_att,
                                                      float* __restrict__ hs,
                                                      float* __restrict__ logitp,
                                                      int* __restrict__ ctrl) {
  __shared__ int s_role;
  const int tid = threadIdx.x;

  if (tid == 0) {
    int xcd;
    asm volatile("s_getreg_b32 %0, hwreg(HW_REG_XCC_ID)" : "=s"(xcd));
    int role = -1;
    const int slot = atomicAdd(&ctrl[xcd], 1);
    if (slot < NWG) {
      if (slot == NWG - 1) atomicCAS(&ctrl[8], -1, xcd);
      int wnr;
      while ((wnr = __hip_atomic_load(&ctrl[8], __ATOMIC_RELAXED,
                                      __HIP_MEMORY_SCOPE_AGENT)) < 0) {
        __builtin_amdgcn_s_sleep(16);
      }
      if (wnr == xcd) role = slot;
    }
    s_role = role;
  }
  __syncthreads();
  const int g = s_role;
  if (g < 0) return;

  const int rg = tid >> 5;   // 0..15 row-group (6 rows each)
  const int kc = tid & 31;   // 0..31 k-chunk (16 k each)

  // W_hh slice in registers as float2 pairs: w2[r][m] = row(rg*6+r),
  // k = kc*16 + 2m .. +1
  v2f w2[6][8];
#pragma unroll
  for (int r = 0; r < 6; ++r) {
    const int lr = rg * 6 + r;                      // 0..95: [gate*32 + elem]
    const int grow = (lr >> 5) * HD + g * 32 + (lr & 31);
    const v2f* wv = (const v2f*)(W_hh + (size_t)grow * HD + kc * 16);
#pragma unroll
    for (int m = 0; m < 8; ++m) w2[r][m] = wv[m];
  }

  // hT2 pair layout: h[k] with k = kc*16 + 2*j2 + e at hT2[j2*32+kc][e]
  __shared__ v2f hT2[256];
  __shared__ float ghb[96];
  __shared__ float bhh_s[96];

  if (tid < 96) bhh_s[tid] = b_hh[(tid >> 5) * HD + g * 32 + (tid & 31)];
  float wa = 0.f;
  if (tid < 32) wa = w_att[g * 32 + tid];

  unsigned int* hs_u = (unsigned int*)hs;

  for (int t = 0; t < T_STEPS; ++t) {
    // gate inputs issued early on the gate lanes (overlap with poll)
    float gi_r = 0.f, gi_z = 0.f, gi_n = 0.f;
    if (tid < 32) {
      const float* gp = gi + (size_t)t * G3HD + g * 32 + tid;
      gi_r = gp[0];
      gi_z = gp[HD];
      gi_n = gp[2 * HD];
    }

    if (tid < 64) {  // wave 0: poll full h[t-1], 8 words = 4 u64 per lane
      v2f hp[4];
      if (t == 0) {
#pragma unroll
        for (int m = 0; m < 4; ++m) hp[m] = (v2f)(0.f);
      } else {
        const unsigned long long* p64 =
            (const unsigned long long*)(hs_u + (size_t)(t - 1) * HD + tid * 8);
        unsigned long long u[4];
        bool ok;
        do {
          ok = true;
#pragma unroll
          for (int m = 0; m < 4; ++m)
            u[m] = __hip_atomic_load(p64 + m, __ATOMIC_RELAXED, __HIP_MEMORY_SCOPE_AGENT);
#pragma unroll
          for (int m = 0; m < 4; ++m)
            ok &= ((unsigned int)u[m] != SENT) & ((unsigned int)(u[m] >> 32) != SENT);
        } while (!ok);
#pragma unroll
        for (int m = 0; m < 4; ++m) {
          hp[m].x = __uint_as_float((unsigned int)u[m]);
          hp[m].y = __uint_as_float((unsigned int)(u[m] >> 32));
        }
      }
#pragma unroll
      for (int m = 0; m < 4; ++m) {
        const int k = tid * 8 + 2 * m;
        hT2[((k & 15) >> 1) * 32 + (k >> 4)] = hp[m];
      }
    }
    __syncthreads();  // B1: hT2 ready

    v2f acc[6];
#pragma unroll
    for (int r = 0; r < 6; ++r) acc[r] = (v2f)(0.f);
#pragma unroll
    for (int m = 0; m < 8; ++m) {
      const v2f hv = hT2[m * 32 + kc];
#pragma unroll
      for (int r = 0; r < 6; ++r) acc[r] = __builtin_elementwise_fma(w2[r][m], hv, acc[r]);
    }
    float s[6];
#pragma unroll
    for (int r = 0; r < 6; ++r) s[r] = acc[r].x + acc[r].y;
#pragma unroll
    for (int mask = 1; mask <= 16; mask <<= 1) {
#pragma unroll
      for (int r = 0; r < 6; ++r) s[r] += __shfl_xor(s[r], mask);
    }
    if (kc < 6) {
      float v = s[0];
      v = (kc == 1) ? s[1] : v;
      v = (kc == 2) ? s[2] : v;
      v = (kc == 3) ? s[3] : v;
      v = (kc == 4) ? s[4] : v;
      v = (kc == 5) ? s[5] : v;
      const int row = rg * 6 + kc;
      ghb[row] = v + bhh_s[row];
    }
    __syncthreads();  // B2: ghb ready

    if (tid < 32) {
      const int j = tid;
      const float x_r = gi_r + ghb[j];
      const float x_z = gi_z + ghb[32 + j];
      const float ghn = ghb[64 + j];
      const float r = __builtin_amdgcn_rcpf(1.f + __expf(-x_r));
      const float z = __builtin_amdgcn_rcpf(1.f + __expf(-x_z));
      const float y = gi_n + r * ghn;
      const float n = 1.f - 2.f * __builtin_amdgcn_rcpf(__expf(2.f * y) + 1.f);
      const int kg = g * 32 + j;
      const float hprev = ((const float*)hT2)[(((kg & 15) >> 1) * 32 + (kg >> 4)) * 2 + (kg & 1)];
      const float hnew = n + z * (hprev - n);
      __hip_atomic_store(hs_u + (size_t)t * HD + kg, __float_as_uint(hnew),
                         __ATOMIC_RELAXED, __HIP_MEMORY_SCOPE_AGENT);
      float lp = wa * hnew;
      lp += __shfl_xor(lp, 1);
      lp += __shfl_xor(lp, 2);
      lp += __shfl_xor(lp, 4);
      lp += __shfl_xor(lp, 8);
      lp += __shfl_xor(lp, 16);
      if (j == 0) logitp[t * NWG + g] = lp;
    }
  }
}

// ---------------------------------------------------------------------------
// Softmax over 4096 logits (reduce 16 partials each), write alpha; zero out.
// ---------------------------------------------------------------------------
__global__ __launch_bounds__(256) void softmax_kernel(const float* __restrict__ logitp,
                                                      float* __restrict__ alpha,
                                                      float* __restrict__ out) {
  __shared__ float tmp[4];
  const int tid = threadIdx.x;
  float l[16];
  float m = -1e30f;
#pragma unroll
  for (int i = 0; i < 16; ++i) {
    const int t = i * 256 + tid;
    float s = 0.f;
#pragma unroll
    for (int gg = 0; gg < NWG; ++gg) s += logitp[t * NWG + gg];
    l[i] = s;
    m = fmaxf(m, s);
  }
#pragma unroll
  for (int o = 32; o > 0; o >>= 1) m = fmaxf(m, __shfl_xor(m, o));
  if ((tid & 63) == 0) tmp[tid >> 6] = m;
  __syncthreads();
  m = fmaxf(fmaxf(tmp[0], tmp[1]), fmaxf(tmp[2], tmp[3]));
  __syncthreads();
  float e[16];
  float s = 0.f;
#pragma unroll
  for (int i = 0; i < 16; ++i) {
    e[i] = expf(l[i] - m);
    s += e[i];
  }
#pragma unroll
  for (int o = 32; o > 0; o >>= 1) s += __shfl_xor(s, o);
  if ((tid & 63) == 0) tmp[tid >> 6] = s;
  __syncthreads();
  s = tmp[0] + tmp[1] + tmp[2] + tmp[3];
  const float inv = 1.f / s;
#pragma unroll
  for (int i = 0; i < 16; ++i) alpha[i * 256 + tid] = e[i] * inv;
  out[tid] = 0.f;
  out[256 + tid] = 0.f;
}

// ---------------------------------------------------------------------------
// out[j] = sum_t alpha[t] * hs[t][j].  128 WGs: 2 j-halves x 64 t-chunks.
// ---------------------------------------------------------------------------
__global__ __launch_bounds__(256) void wsum_kernel(const float* __restrict__ alpha,
                                                   const float* __restrict__ hs,
                                                   float* __restrict__ out) {
  const int tid = threadIdx.x;
  const int jblk = (blockIdx.x & 1) * 256;
  const int tc = blockIdx.x >> 1;
  float acc = 0.f;
  for (int tt = 0; tt < 64; ++tt) {
    const int t = tc * 64 + tt;
    acc += alpha[t] * hs[(size_t)t * HD + jblk + tid];
  }
  atomicAdd(&out[jblk + tid], acc);
}

extern "C" void kernel_launch(void* const* d_in, const int* in_sizes, int n_in,
                              void* d_out, int out_size, void* d_ws, size_t ws_size,
                              hipStream_t stream) {
  const float* H     = (const float*)d_in[0];
  // d_in[1] = TE, unused by the reference
  const float* X_emb = (const float*)d_in[2];
  const float* W_ih  = (const float*)d_in[3];
  const float* W_hh  = (const float*)d_in[4];
  const float* b_ih  = (const float*)d_in[5];
  const float* b_hh  = (const float*)d_in[6];
  const float* w_att = (const float*)d_in[7];
  float* out = (float*)d_out;

  char* ws = (char*)d_ws;
  float* visit  = (float*)(ws + 0);          //  8 MB: 4096x512
  float* gi     = (float*)(ws + 8388608);    // 25 MB: 4096x1536
  float* hs     = (float*)(ws + 33554432);   //  8 MB: 4096x512
  float* logitp = (float*)(ws + 41943040);   // 256 KB: 4096x16
  float* alpha  = (float*)(ws + 42205184);   // 16 KB
  int*   ctrl   = (int*)(ws + 42221568);     // [0..7] per-XCD counters, [8] winner

  // sentinel-fill hs (0xFFFFFFFF = -NaN, unreachable from finite GRU math)
  hipMemsetAsync(hs, 0xFF, (size_t)T_STEPS * HD * sizeof(float), stream);
  hipMemsetAsync(ctrl, 0, 8 * sizeof(int), stream);
  hipMemsetAsync(ctrl + 8, 0xFF, sizeof(int), stream);  // winner = -1

  gemm1_kernel<<<dim3(64, 8), 256, 0, stream>>>(H, X_emb, visit);
  gemm2_kernel<<<dim3(64, 24), 256, 0, stream>>>(visit, W_ih, b_ih, gi);
  scan_kernel<<<256, 512, 0, stream>>>(gi, W_hh, b_hh, w_att, hs, logitp, ctrl);
  softmax_kernel<<<1, 256, 0, stream>>>(logitp, alpha, out);
  wsum_kernel<<<128, 256, 0, stream>>>(alpha, hs, out);
}